// Round 10
// baseline (16807.722 us; speedup 1.0000x reference)
//
#include <hip/hip_runtime.h>
#include <cmath>

#define LEAK 0.95f
#define ILEAK 0.05f

typedef float f4 __attribute__((ext_vector_type(4)));
typedef unsigned long long ull;

// ---------------- Phase 1: u = x @ W_in^T (fp32 tiled GEMM) ----------------
__global__ __launch_bounds__(256) void resv_gemm_uin(
    const float* __restrict__ A, const float* __restrict__ Bm,
    float* __restrict__ C, int M, int N, int K)
{
    __shared__ float As[16][68];
    __shared__ float Bs[16][68];
    const int tid = threadIdx.x;
    const int m0 = blockIdx.y * 64;
    const int n0 = blockIdx.x * 64;
    const int lm = tid >> 2;
    const int lk = (tid & 3) * 4;
    const int ty = tid >> 4;
    const int tx = tid & 15;

    float acc[4][4];
#pragma unroll
    for (int i = 0; i < 4; ++i)
#pragma unroll
        for (int j = 0; j < 4; ++j) acc[i][j] = 0.f;

    const float* Aptr = A + (size_t)(m0 + lm) * K + lk;
    const float* Bptr = Bm + (size_t)(n0 + lm) * K + lk;

    for (int k0 = 0; k0 < K; k0 += 16) {
        float4 av = *(const float4*)(Aptr + k0);
        float4 bv = *(const float4*)(Bptr + k0);
        __syncthreads();
        As[lk + 0][lm] = av.x; As[lk + 1][lm] = av.y;
        As[lk + 2][lm] = av.z; As[lk + 3][lm] = av.w;
        Bs[lk + 0][lm] = bv.x; Bs[lk + 1][lm] = bv.y;
        Bs[lk + 2][lm] = bv.z; Bs[lk + 3][lm] = bv.w;
        __syncthreads();
#pragma unroll
        for (int kk = 0; kk < 16; ++kk) {
            float4 a = *(const float4*)(&As[kk][ty * 4]);
            float4 b = *(const float4*)(&Bs[kk][tx * 4]);
            acc[0][0] += a.x * b.x; acc[0][1] += a.x * b.y; acc[0][2] += a.x * b.z; acc[0][3] += a.x * b.w;
            acc[1][0] += a.y * b.x; acc[1][1] += a.y * b.y; acc[1][2] += a.y * b.z; acc[1][3] += a.y * b.w;
            acc[2][0] += a.z * b.x; acc[2][1] += a.z * b.y; acc[2][2] += a.z * b.z; acc[2][3] += a.z * b.w;
            acc[3][0] += a.w * b.x; acc[3][1] += a.w * b.y; acc[3][2] += a.w * b.z; acc[3][3] += a.w * b.w;
        }
    }
    float* Cp = C + (size_t)(m0 + ty * 4) * N + n0 + tx * 4;
#pragma unroll
    for (int i = 0; i < 4; ++i) {
        float4 v = make_float4(acc[i][0], acc[i][1], acc[i][2], acc[i][3]);
        *(float4*)(Cp + (size_t)i * N) = v;
    }
}

// ---------------- Phase 2: reservoir recurrence, data-tagged sync ---------
// EXACT round-7 sync skeleton (proven best: tag-poll the data, atomic_store
// publish, 3 barriers). SINGLE change: compute decomposition. Old: 32-way
// broadcast reads, 128 ds_read_b128/lane (512 LDS instrs/CU/step ~2.5us of
// LDS issue). New: wave = 8 groups x 8 lanes; prevL is [k][b]-interleaved so
// one b128 read = one k x 4 batches; lane owns 4 rows x 32 k's -> 32 reads
// per lane (128 instrs/CU/step, 8 unique 16B addrs/instr = conflict-free),
// then a 3-round 8-lane shuffle reduce. pairs layout moves to [slot][g][k][b].
__global__ __launch_bounds__(256, 1) void resv_recur(
    const float* __restrict__ Wres,   // [1024][1024]
    float* __restrict__ out,          // [32][2048][1024] (pre-filled with u)
    ull* __restrict__ pairs)          // ws: [2 slots][8 g][1024 k][4 b] 8B pairs
{
    constexpr int H = 1024, S = 2048;
    extern __shared__ float sm[];
    float* prevL = sm;                 // [1024 k][4 b] (16 KB)
    float* uL    = sm + 4096;          // [2][2048] double-buffered u (16 KB)
    float* red   = sm + 8192;          // [4 q][32 row] f4-over-b (2 KB)

    const int tid = threadIdx.x;
    const int g  = blockIdx.x & 7;
    const int r  = blockIdx.x >> 3;
    const int h0 = r * 32;
    const int b0 = g * 4;

    const int w   = tid >> 6;          // wave = k-quarter
    const int l   = tid & 63;
    const int gI  = l >> 3;            // row-group 0..7 (rows 4gI..4gI+3)
    const int li  = l & 7;             // k-lane within group
    const int kbase = w * 256 + li;    // lane covers k = kbase + 8*j, j=0..31

    // ---- one-time: W[h0+4gI+rr][kbase+8j] into 128 scalar registers ----
    float Wreg[128];
#pragma unroll
    for (int rr = 0; rr < 4; ++rr)
#pragma unroll
        for (int j = 0; j < 32; ++j)
            Wreg[rr * 32 + j] =
                Wres[(size_t)(h0 + 4 * gI + rr) * H + kbase + 8 * j];

    const int fb  = tid >> 5;          // finish: batch (tid<128)
    const int frw = tid & 31;          // finish: row
    float pv = 0.f;                    // tid<128: own element's previous value

    for (int t = 0; t < S; ++t) {
        // ---- stage u[t..t+15] into double buffer (own region, plain) ----
        if ((t & 15) == 0) {
            float* uB = uL + ((t >> 4) & 1) * 2048;
            for (int c = tid; c < 512; c += 256) {
                int rw4 = c & 7, b = (c >> 3) & 3, tt = c >> 5;
                const float4* src =
                    (const float4*)(out + ((size_t)(b0 + b) * S + (t + tt)) * H + h0);
                ((float4*)uB)[(tt * 4 + b) * 8 + rw4] = src[rw4];
            }
        }
        // ---- poll-load prev: 16 pairs/lane, retry until all tags == t ----
        {
            const ull* src = pairs + ((size_t)((t & 1) * 8 + g)) * 4096;
            ull v[16];
            const unsigned tgt = (unsigned)t;
            for (;;) {
#pragma unroll
                for (int c = 0; c < 16; ++c)
                    v[c] = __hip_atomic_load(src + c * 256 + tid, __ATOMIC_RELAXED,
                                             __HIP_MEMORY_SCOPE_AGENT);
                int ok = 1;
#pragma unroll
                for (int c = 0; c < 16; ++c)
                    ok &= ((unsigned)(v[c] >> 32) == tgt);
                if (__all(ok)) break;
            }
#pragma unroll
            for (int c = 0; c < 16; ++c)
                prevL[c * 256 + tid] = __uint_as_float((unsigned)v[c]);
        }
        __syncthreads();

        // ---- compute: acc[rr](f4 over b) = sum_j W[rr][k]*prev[k][0..3] ----
        f4 a0 = (f4)(0.f), a1 = (f4)(0.f), a2 = (f4)(0.f), a3 = (f4)(0.f);
        const f4* P = (const f4*)prevL;
#pragma unroll
        for (int j = 0; j < 32; ++j) {
            f4 pk = P[kbase + 8 * j];   // one k, 4 batches; 8 uniq addrs/instr
            a0 += Wreg[0 * 32 + j] * pk;
            a1 += Wreg[1 * 32 + j] * pk;
            a2 += Wreg[2 * 32 + j] * pk;
            a3 += Wreg[3 * 32 + j] * pk;
        }
        // reduce over the 8 k-lanes of the group (xor 1,2,4)
#pragma unroll
        for (int m = 1; m <= 4; m <<= 1) {
            a0.x += __shfl_xor(a0.x, m, 64); a0.y += __shfl_xor(a0.y, m, 64);
            a0.z += __shfl_xor(a0.z, m, 64); a0.w += __shfl_xor(a0.w, m, 64);
            a1.x += __shfl_xor(a1.x, m, 64); a1.y += __shfl_xor(a1.y, m, 64);
            a1.z += __shfl_xor(a1.z, m, 64); a1.w += __shfl_xor(a1.w, m, 64);
            a2.x += __shfl_xor(a2.x, m, 64); a2.y += __shfl_xor(a2.y, m, 64);
            a2.z += __shfl_xor(a2.z, m, 64); a2.w += __shfl_xor(a2.w, m, 64);
            a3.x += __shfl_xor(a3.x, m, 64); a3.y += __shfl_xor(a3.y, m, 64);
            a3.z += __shfl_xor(a3.z, m, 64); a3.w += __shfl_xor(a3.w, m, 64);
        }
        if (li == 0) {
            f4* rd = (f4*)red + w * 32 + 4 * gI;
            rd[0] = a0; rd[1] = a1; rd[2] = a2; rd[3] = a3;
        }
        __syncthreads();

        // ---- finish (tid<128): 1 element each; publish tagged pair ----
        if (tid < 128) {
            float sum = red[(0 * 32 + frw) * 4 + fb] + red[(1 * 32 + frw) * 4 + fb]
                      + red[(2 * 32 + frw) * 4 + fb] + red[(3 * 32 + frw) * 4 + fb];
            float uv = uL[((t >> 4) & 1) * 2048 + (((t & 15) * 4 + fb) << 5) + frw];
            float ns = LEAK * tanhf(uv + sum) + ILEAK * pv;
            pv = ns;
            ull pk = ((ull)(unsigned)(t + 1) << 32) | (ull)__float_as_uint(ns);
            __hip_atomic_store(
                pairs + ((size_t)(((t + 1) & 1) * 8 + g)) * 4096
                      + (size_t)(h0 + frw) * 4 + fb,
                pk, __ATOMIC_RELAXED, __HIP_MEMORY_SCOPE_AGENT);
            out[((size_t)(b0 + fb) * S + t) * H + h0 + frw] = ns;
        }
        // no drain, no flag: consumers poll the tagged data itself.
        __syncthreads();
    }
}

extern "C" void kernel_launch(void* const* d_in, const int* in_sizes, int n_in,
                              void* d_out, int out_size, void* d_ws, size_t ws_size,
                              hipStream_t stream)
{
    const float* x    = (const float*)d_in[0];   // [32][2048][512]
    const float* Win  = (const float*)d_in[1];   // [1024][512]
    const float* Wres = (const float*)d_in[2];   // [1024][1024]
    float* out = (float*)d_out;                  // [32][2048][1024]

    ull* pairs = (ull*)d_ws;                     // 2*8*1024*4*8 = 524288 B

    // zero pairs every launch: (tag 0, 0.0f) == step-0 initial state
    hipMemsetAsync(d_ws, 0, 524288, stream);

    // phase 1: u = x @ W_in^T into d_out
    dim3 gemm_grid(1024 / 64, 65536 / 64);
    resv_gemm_uin<<<gemm_grid, 256, 0, stream>>>(x, Win, out, 65536, 1024, 512);

    // phase 2: recurrence. 96KB dynamic LDS pins exactly 1 wg/CU
    // (co-residency of all 256 wgs proven rounds 1-9).
    constexpr int kLds = 96 * 1024;
    hipFuncSetAttribute((const void*)resv_recur,
                        hipFuncAttributeMaxDynamicSharedMemorySize, kLds);
    resv_recur<<<dim3(256), dim3(256), kLds, stream>>>(Wres, out, pairs);
}

// Round 11
// 16004.558 us; speedup vs baseline: 1.0502x; 1.0502x over previous
//
#include <hip/hip_runtime.h>
#include <cmath>

#define LEAK 0.95f
#define ILEAK 0.05f

typedef float f4 __attribute__((ext_vector_type(4)));
typedef unsigned long long ull;

// ---------------- Phase 1: u = x @ W_in^T (fp32 tiled GEMM) ----------------
__global__ __launch_bounds__(256) void resv_gemm_uin(
    const float* __restrict__ A, const float* __restrict__ Bm,
    float* __restrict__ C, int M, int N, int K)
{
    __shared__ float As[16][68];
    __shared__ float Bs[16][68];
    const int tid = threadIdx.x;
    const int m0 = blockIdx.y * 64;
    const int n0 = blockIdx.x * 64;
    const int lm = tid >> 2;
    const int lk = (tid & 3) * 4;
    const int ty = tid >> 4;
    const int tx = tid & 15;

    float acc[4][4];
#pragma unroll
    for (int i = 0; i < 4; ++i)
#pragma unroll
        for (int j = 0; j < 4; ++j) acc[i][j] = 0.f;

    const float* Aptr = A + (size_t)(m0 + lm) * K + lk;
    const float* Bptr = Bm + (size_t)(n0 + lm) * K + lk;

    for (int k0 = 0; k0 < K; k0 += 16) {
        float4 av = *(const float4*)(Aptr + k0);
        float4 bv = *(const float4*)(Bptr + k0);
        __syncthreads();
        As[lk + 0][lm] = av.x; As[lk + 1][lm] = av.y;
        As[lk + 2][lm] = av.z; As[lk + 3][lm] = av.w;
        Bs[lk + 0][lm] = bv.x; Bs[lk + 1][lm] = bv.y;
        Bs[lk + 2][lm] = bv.z; Bs[lk + 3][lm] = bv.w;
        __syncthreads();
#pragma unroll
        for (int kk = 0; kk < 16; ++kk) {
            float4 a = *(const float4*)(&As[kk][ty * 4]);
            float4 b = *(const float4*)(&Bs[kk][tx * 4]);
            acc[0][0] += a.x * b.x; acc[0][1] += a.x * b.y; acc[0][2] += a.x * b.z; acc[0][3] += a.x * b.w;
            acc[1][0] += a.y * b.x; acc[1][1] += a.y * b.y; acc[1][2] += a.y * b.z; acc[1][3] += a.y * b.w;
            acc[2][0] += a.z * b.x; acc[2][1] += a.z * b.y; acc[2][2] += a.z * b.z; acc[2][3] += a.z * b.w;
            acc[3][0] += a.w * b.x; acc[3][1] += a.w * b.y; acc[3][2] += a.w * b.z; acc[3][3] += a.w * b.w;
        }
    }
    float* Cp = C + (size_t)(m0 + ty * 4) * N + n0 + tx * 4;
#pragma unroll
    for (int i = 0; i < 4; ++i) {
        float4 v = make_float4(acc[i][0], acc[i][1], acc[i][2], acc[i][3]);
        *(float4*)(Cp + (size_t)i * N) = v;
    }
}

// ---------------- Phase 2: reservoir recurrence, data-tagged sync ---------
// r10 decomposition with the three identified defects fixed:
//  (1) FULL-LINE publish in [k][b] layout: finish lane map fb=tid&3,
//      frw=tid>>2 -> pair index h0*4+tid (128 consecutive ull = 8 full
//      lines). r10's frw-major map scattered at stride 32B (WRITE 1333MB).
//  (2) wave-private poll: wave w polls+stages only quarter w of the group's
//      4096 pairs (16 coalesced loads/lane). No post-poll barrier (prevL
//      quarter is wave-private). Group induction safe: each wg's 4 waves
//      cover all quarters and the pre-finish barrier joins them.
//  (3) ONE barrier/step: red double-buffered (red[t&1]), uL double-buffered,
//      prevL wave-private. (r7 had 3 barriers.)
// Compute: 32 ds_read_b128/lane (8 uniq addrs/instr, conflict-free), 16 FMA
// per read, 3-round 8-lane shuffle reduce. Tags make stale reads benign.
__global__ __launch_bounds__(256, 1) void resv_recur(
    const float* __restrict__ Wres,   // [1024][1024]
    float* __restrict__ out,          // [32][2048][1024] (pre-filled with u)
    ull* __restrict__ pairs)          // ws: [2 slots][8 g][1024 h][4 b] pairs
{
    constexpr int H = 1024, S = 2048;
    extern __shared__ float sm[];
    float* prevL = sm;                 // [1024 h][4 b] floats (16 KB)
    float* uL    = sm + 4096;          // [2][2048] double-buffered u (16 KB)
    float* red   = sm + 8192;          // [2][4 q][32 row][4 b] dbuf (4 KB)

    const int tid = threadIdx.x;
    const int g  = blockIdx.x & 7;
    const int r  = blockIdx.x >> 3;
    const int h0 = r * 32;
    const int b0 = g * 4;

    const int w  = tid >> 6;           // wave = k-quarter (owns h w*256..+255)
    const int l  = tid & 63;
    const int gI = l >> 3;             // row-group 0..7 (rows 4gI..4gI+3)
    const int li = l & 7;              // k-lane within group

    // ---- one-time: W[h0+4gI+rr][w*256+li+8j] into 128 scalar registers ----
    float Wreg[128];
#pragma unroll
    for (int rr = 0; rr < 4; ++rr)
#pragma unroll
        for (int j = 0; j < 32; ++j)
            Wreg[rr * 32 + j] =
                Wres[(size_t)(h0 + 4 * gI + rr) * H + (w * 256 + li + 8 * j)];

    const int fb  = tid & 3;           // finish: batch
    const int frw = tid >> 2;          // finish: row (tid<128 -> frw<32)
    float pv = 0.f;                    // finish thread's own previous value

    for (int t = 0; t < S; ++t) {
        // ---- stage u[t..t+15] into double buffer (all waves, own region) --
        if ((t & 15) == 0) {
            float* uB = uL + ((t >> 4) & 1) * 2048;
            for (int c = tid; c < 512; c += 256) {
                int rw4 = c & 7, b = (c >> 3) & 3, tt = c >> 5;
                const float4* src =
                    (const float4*)(out + ((size_t)(b0 + b) * S + (t + tt)) * H + h0);
                ((float4*)uB)[(tt * 4 + b) * 8 + rw4] = src[rw4];
            }
        }
        // ---- wave-private poll of quarter w (1024 pairs, 16/lane) ----
        {
            const ull* src = pairs + ((size_t)((t & 1) * 8 + g)) * 4096
                           + (size_t)w * 1024;
            const unsigned tgt = (unsigned)t;
            ull v[16];
            for (;;) {
#pragma unroll
                for (int c = 0; c < 16; ++c)
                    v[c] = __hip_atomic_load(src + c * 64 + l, __ATOMIC_RELAXED,
                                             __HIP_MEMORY_SCOPE_AGENT);
                int ok = 1;
#pragma unroll
                for (int c = 0; c < 16; ++c)
                    ok &= ((unsigned)(v[c] >> 32) == tgt);
                if (__all(ok)) break;
            }
#pragma unroll
            for (int c = 0; c < 16; ++c)
                prevL[w * 1024 + c * 64 + l] = __uint_as_float((unsigned)v[c]);
        }
        // no barrier: prevL quarter is wave-private (written+read by wave w)

        // ---- compute: 4 rows x 4 batches per lane over quarter-k ----
        f4 a0 = (f4)(0.f), a1 = (f4)(0.f), a2 = (f4)(0.f), a3 = (f4)(0.f);
        const f4* P = (const f4*)prevL;    // P[h] = prev[h][0..3]
#pragma unroll
        for (int j = 0; j < 32; ++j) {
            f4 pk = P[w * 256 + li + 8 * j];  // 8 uniq 16B addrs/instr
            a0 += Wreg[j]      * pk;
            a1 += Wreg[32 + j] * pk;
            a2 += Wreg[64 + j] * pk;
            a3 += Wreg[96 + j] * pk;
        }
        // reduce over the 8 k-lanes (xor 1,2,4)
#define RED8(A) \
        A.x += __shfl_xor(A.x, m, 64); A.y += __shfl_xor(A.y, m, 64); \
        A.z += __shfl_xor(A.z, m, 64); A.w += __shfl_xor(A.w, m, 64);
#pragma unroll
        for (int m = 1; m <= 4; m <<= 1) { RED8(a0) RED8(a1) RED8(a2) RED8(a3) }
#undef RED8
        float* redB = red + (t & 1) * 512;
        if (li == 0) {
            f4* rd = (f4*)redB + (w * 32 + 4 * gI);
            rd[0] = a0; rd[1] = a1; rd[2] = a2; rd[3] = a3;
        }
        __syncthreads();   // the ONE barrier: red writes -> finish reads

        // ---- finish (tid<128): publish tagged pair, FULL-LINE order ----
        if (tid < 128) {
            float sum = redB[(0 * 32 + frw) * 4 + fb] + redB[(1 * 32 + frw) * 4 + fb]
                      + redB[(2 * 32 + frw) * 4 + fb] + redB[(3 * 32 + frw) * 4 + fb];
            float uv = uL[((t >> 4) & 1) * 2048 + (((t & 15) * 4 + fb) << 5) + frw];
            float ns = LEAK * tanhf(uv + sum) + ILEAK * pv;
            pv = ns;
            ull pk = ((ull)(unsigned)(t + 1) << 32) | (ull)__float_as_uint(ns);
            // pair index (h0+frw)*4+fb == h0*4 + tid: 128 consecutive ull
            __hip_atomic_store(
                pairs + ((size_t)(((t + 1) & 1) * 8 + g)) * 4096 + h0 * 4 + tid,
                pk, __ATOMIC_RELAXED, __HIP_MEMORY_SCOPE_AGENT);
            out[((size_t)(b0 + fb) * S + t) * H + h0 + frw] = ns;
        }
        // no trailing barrier: red dbuf'd, prevL wave-private, uL dbuf'd,
        // pairs overrun covered by the group induction (4 waves cover all
        // quarters + the pre-finish barrier joins them).
    }
}

extern "C" void kernel_launch(void* const* d_in, const int* in_sizes, int n_in,
                              void* d_out, int out_size, void* d_ws, size_t ws_size,
                              hipStream_t stream)
{
    const float* x    = (const float*)d_in[0];   // [32][2048][512]
    const float* Win  = (const float*)d_in[1];   // [1024][512]
    const float* Wres = (const float*)d_in[2];   // [1024][1024]
    float* out = (float*)d_out;                  // [32][2048][1024]

    ull* pairs = (ull*)d_ws;                     // 2*8*4096*8 = 524288 B

    // zero pairs every launch: (tag 0, 0.0f) == step-0 initial state
    hipMemsetAsync(d_ws, 0, 524288, stream);

    // phase 1: u = x @ W_in^T into d_out
    dim3 gemm_grid(1024 / 64, 65536 / 64);
    resv_gemm_uin<<<gemm_grid, 256, 0, stream>>>(x, Win, out, 65536, 1024, 512);

    // phase 2: recurrence. 96KB dynamic LDS pins exactly 1 wg/CU
    // (co-residency of all 256 wgs proven rounds 1-10).
    constexpr int kLds = 96 * 1024;
    hipFuncSetAttribute((const void*)resv_recur,
                        hipFuncAttributeMaxDynamicSharedMemorySize, kLds);
    resv_recur<<<dim3(256), dim3(256), kLds, stream>>>(Wres, out, pairs);
}

// Round 12
// 11552.592 us; speedup vs baseline: 1.4549x; 1.3854x over previous
//
#include <hip/hip_runtime.h>
#include <cmath>

#define LEAK 0.95f
#define ILEAK 0.05f

typedef float f4 __attribute__((ext_vector_type(4)));
typedef unsigned long long ull;

// ---------------- Phase 1: u = x @ W_in^T (fp32 tiled GEMM) ----------------
__global__ __launch_bounds__(256) void resv_gemm_uin(
    const float* __restrict__ A, const float* __restrict__ Bm,
    float* __restrict__ C, int M, int N, int K)
{
    __shared__ float As[16][68];
    __shared__ float Bs[16][68];
    const int tid = threadIdx.x;
    const int m0 = blockIdx.y * 64;
    const int n0 = blockIdx.x * 64;
    const int lm = tid >> 2;
    const int lk = (tid & 3) * 4;
    const int ty = tid >> 4;
    const int tx = tid & 15;

    float acc[4][4];
#pragma unroll
    for (int i = 0; i < 4; ++i)
#pragma unroll
        for (int j = 0; j < 4; ++j) acc[i][j] = 0.f;

    const float* Aptr = A + (size_t)(m0 + lm) * K + lk;
    const float* Bptr = Bm + (size_t)(n0 + lm) * K + lk;

    for (int k0 = 0; k0 < K; k0 += 16) {
        float4 av = *(const float4*)(Aptr + k0);
        float4 bv = *(const float4*)(Bptr + k0);
        __syncthreads();
        As[lk + 0][lm] = av.x; As[lk + 1][lm] = av.y;
        As[lk + 2][lm] = av.z; As[lk + 3][lm] = av.w;
        Bs[lk + 0][lm] = bv.x; Bs[lk + 1][lm] = bv.y;
        Bs[lk + 2][lm] = bv.z; Bs[lk + 3][lm] = bv.w;
        __syncthreads();
#pragma unroll
        for (int kk = 0; kk < 16; ++kk) {
            float4 a = *(const float4*)(&As[kk][ty * 4]);
            float4 b = *(const float4*)(&Bs[kk][tx * 4]);
            acc[0][0] += a.x * b.x; acc[0][1] += a.x * b.y; acc[0][2] += a.x * b.z; acc[0][3] += a.x * b.w;
            acc[1][0] += a.y * b.x; acc[1][1] += a.y * b.y; acc[1][2] += a.y * b.z; acc[1][3] += a.y * b.w;
            acc[2][0] += a.z * b.x; acc[2][1] += a.z * b.y; acc[2][2] += a.z * b.z; acc[2][3] += a.z * b.w;
            acc[3][0] += a.w * b.x; acc[3][1] += a.w * b.y; acc[3][2] += a.w * b.z; acc[3][3] += a.w * b.w;
        }
    }
    float* Cp = C + (size_t)(m0 + ty * 4) * N + n0 + tx * 4;
#pragma unroll
    for (int i = 0; i < 4; ++i) {
        float4 v = make_float4(acc[i][0], acc[i][1], acc[i][2], acc[i][3]);
        *(float4*)(Cp + (size_t)i * N) = v;
    }
}

// ---------------- Phase 2: reservoir recurrence, data-tagged sync ---------
// BYTE-EXACT round-7 structure (proven best: 11.26ms) with ONE change:
// sentinel polling. r7's wait loop reloaded all 16 pairs/lane per retry
// round (8MB/round across the chip, saturating L3 and queueing ahead of the
// critical publish/detect transactions). Now the wait loop polls only 4
// sentinel pairs/lane (c=0,5,10,15: one per producer row-block, batch-
// diverse); when fresh, bulk-load the remaining 12 and tag-verify (any
// stale -> full r7-style retry, so correctness/deadlock-freedom identical).
// Wait-round traffic drops 4x, below the L3 saturation knee.
__global__ __launch_bounds__(256, 1) void resv_recur(
    const float* __restrict__ Wres,   // [1024][1024]
    float* __restrict__ out,          // [32][2048][1024] (pre-filled with u)
    ull* __restrict__ pairs)          // ws: [2 slots][32 b][1024 h] 8B pairs
{
    constexpr int H = 1024, S = 2048;
    extern __shared__ float sm[];
    float* prevL = sm;                 // [4][1024] b-major (16 KB)
    float* uL    = sm + 4096;          // [2][2048] double-buffered u (16 KB)
    float* red   = sm + 8192;          // [4 q][32 row] f4-over-b (2 KB)

    const int tid = threadIdx.x;
    const int g  = blockIdx.x & 7;
    const int r  = blockIdx.x >> 3;
    const int h0 = r * 32;
    const int b0 = g * 4;

    const int w   = tid >> 6;          // wave = k-quarter
    const int l   = tid & 63;
    const int lh  = l >> 5;            // k-half within quarter
    const int row = l & 31;            // row within this wg's 32-row block
    const int K0  = w * 256 + lh * 128;
    const int kb  = K0 >> 2;           // f4 index base

    // ---- one-time: W_res[h0+row][K0 .. K0+127] into 32 f4 registers ----
    f4 Wreg[32];
    {
        const f4* wsrc = (const f4*)(Wres + (size_t)(h0 + row) * H + K0);
#pragma unroll
        for (int i = 0; i < 32; ++i) Wreg[i] = wsrc[i];
    }

    const int fb  = tid >> 5;          // finish: batch (tid<128)
    const int frw = tid & 31;          // finish: row
    float pv = 0.f;                    // tid<128: own element's previous value

    for (int t = 0; t < S; ++t) {
        // ---- stage u[t..t+15] into double buffer (own region, plain) ----
        if ((t & 15) == 0) {
            float* uB = uL + ((t >> 4) & 1) * 2048;
            for (int c = tid; c < 512; c += 256) {
                int rw4 = c & 7, b = (c >> 3) & 3, tt = c >> 5;
                const float4* src =
                    (const float4*)(out + ((size_t)(b0 + b) * S + (t + tt)) * H + h0);
                ((float4*)uB)[(tt * 4 + b) * 8 + rw4] = src[rw4];
            }
        }
        // ---- poll-load prev: sentinel wait (4/lane), then bulk + verify ----
        {
            const ull* src = pairs + ((size_t)(t & 1) * 32 + b0) * 1024;
            const unsigned tgt = (unsigned)t;
            ull v[16];
            // 1) sentinel wait: c = 0,5,10,15 (one pair per producer block)
            for (;;) {
                ull s0 = __hip_atomic_load(src + 0 * 256 + tid, __ATOMIC_RELAXED,
                                           __HIP_MEMORY_SCOPE_AGENT);
                ull s1 = __hip_atomic_load(src + 5 * 256 + tid, __ATOMIC_RELAXED,
                                           __HIP_MEMORY_SCOPE_AGENT);
                ull s2 = __hip_atomic_load(src + 10 * 256 + tid, __ATOMIC_RELAXED,
                                           __HIP_MEMORY_SCOPE_AGENT);
                ull s3 = __hip_atomic_load(src + 15 * 256 + tid, __ATOMIC_RELAXED,
                                           __HIP_MEMORY_SCOPE_AGENT);
                int ok = ((unsigned)(s0 >> 32) == tgt) & ((unsigned)(s1 >> 32) == tgt)
                       & ((unsigned)(s2 >> 32) == tgt) & ((unsigned)(s3 >> 32) == tgt);
                if (__all(ok)) { v[0] = s0; v[5] = s1; v[10] = s2; v[15] = s3; break; }
            }
            // 2) bulk-load remaining 12, verify; rare stale -> full retry
            for (;;) {
#pragma unroll
                for (int c = 0; c < 16; ++c) {
                    if (c == 0 || c == 5 || c == 10 || c == 15) continue;
                    v[c] = __hip_atomic_load(src + c * 256 + tid, __ATOMIC_RELAXED,
                                             __HIP_MEMORY_SCOPE_AGENT);
                }
                int ok = 1;
#pragma unroll
                for (int c = 0; c < 16; ++c) {
                    if (c == 0 || c == 5 || c == 10 || c == 15) continue;
                    ok &= ((unsigned)(v[c] >> 32) == tgt);
                }
                if (__all(ok)) break;
            }
#pragma unroll
            for (int c = 0; c < 16; ++c)
                prevL[c * 256 + tid] = __uint_as_float((unsigned)v[c]);
        }
        __syncthreads();

        // ---- compute: acc[b] = sum_k W[row][k]*prev[b][k] (broadcast f4s) ----
        float a0 = 0.f, a1 = 0.f, a2 = 0.f, a3 = 0.f;
        const f4* P = (const f4*)prevL;
#pragma unroll
        for (int i = 0; i < 32; ++i) {
            f4 wv = Wreg[i];
            f4 p0 = P[kb + i];
            f4 p1 = P[256 + kb + i];
            f4 p2 = P[512 + kb + i];
            f4 p3 = P[768 + kb + i];
            a0 += wv.x * p0.x + wv.y * p0.y + wv.z * p0.z + wv.w * p0.w;
            a1 += wv.x * p1.x + wv.y * p1.y + wv.z * p1.z + wv.w * p1.w;
            a2 += wv.x * p2.x + wv.y * p2.y + wv.z * p2.z + wv.w * p2.w;
            a3 += wv.x * p3.x + wv.y * p3.y + wv.z * p3.z + wv.w * p3.w;
        }
        // combine the two k-halves (lanes l and l^32 share a row)
        a0 += __shfl_xor(a0, 32, 64);
        a1 += __shfl_xor(a1, 32, 64);
        a2 += __shfl_xor(a2, 32, 64);
        a3 += __shfl_xor(a3, 32, 64);
        if (l < 32) {
            f4 v; v.x = a0; v.y = a1; v.z = a2; v.w = a3;
            ((f4*)red)[w * 32 + row] = v;
        }
        __syncthreads();

        // ---- finish (tid<128): 1 element each; publish tagged pair ----
        if (tid < 128) {
            float sum = red[(0 * 32 + frw) * 4 + fb] + red[(1 * 32 + frw) * 4 + fb]
                      + red[(2 * 32 + frw) * 4 + fb] + red[(3 * 32 + frw) * 4 + fb];
            float uv = uL[((t >> 4) & 1) * 2048 + (((t & 15) * 4 + fb) << 5) + frw];
            float ns = LEAK * tanhf(uv + sum) + ILEAK * pv;
            pv = ns;
            ull pk = ((ull)(unsigned)(t + 1) << 32) | (ull)__float_as_uint(ns);
            __hip_atomic_store(
                pairs + ((size_t)((t + 1) & 1) * 32 + b0 + fb) * 1024 + h0 + frw,
                pk, __ATOMIC_RELAXED, __HIP_MEMORY_SCOPE_AGENT);
            out[((size_t)(b0 + fb) * S + t) * H + h0 + frw] = ns;
        }
        // no drain, no flag: consumers poll the tagged data itself.
        __syncthreads();
    }
}

extern "C" void kernel_launch(void* const* d_in, const int* in_sizes, int n_in,
                              void* d_out, int out_size, void* d_ws, size_t ws_size,
                              hipStream_t stream)
{
    const float* x    = (const float*)d_in[0];   // [32][2048][512]
    const float* Win  = (const float*)d_in[1];   // [1024][512]
    const float* Wres = (const float*)d_in[2];   // [1024][1024]
    float* out = (float*)d_out;                  // [32][2048][1024]

    ull* pairs = (ull*)d_ws;                     // 2*32*1024*8 = 524288 B

    // zero pairs every launch: (tag 0, 0.0f) == step-0 initial state
    hipMemsetAsync(d_ws, 0, 524288, stream);

    // phase 1: u = x @ W_in^T into d_out
    dim3 gemm_grid(1024 / 64, 65536 / 64);
    resv_gemm_uin<<<gemm_grid, 256, 0, stream>>>(x, Win, out, 65536, 1024, 512);

    // phase 2: recurrence. 96KB dynamic LDS pins exactly 1 wg/CU
    // (co-residency of all 256 wgs proven rounds 1-11).
    constexpr int kLds = 96 * 1024;
    hipFuncSetAttribute((const void*)resv_recur,
                        hipFuncAttributeMaxDynamicSharedMemorySize, kLds);
    resv_recur<<<dim3(256), dim3(256), kLds, stream>>>(Wres, out, pairs);
}